// Round 13
// baseline (43.509 us; speedup 1.0000x reference)
//
#include <hip/hip_runtime.h>
#include <cstdint>

#define B_ 2
#define N_ 8192
#define M_ 1024
#define C_ 1152
#define EPS_ 1e-8f
#define NT 32
#define CHUNK 128
#define NBN (N_ / NT)      // 256 n-blocks
#define NBC (C_ / CHUNK)   // 9 c-blocks
#define TRB ((M_ / 64) * (C_ / 64) * B_)   // 576 transpose blocks
#define NNB 256            // threenn blocks (64 points each)
#define CW  (M_ / 8)       // 128 centers per wave

typedef float f32x4 __attribute__((ext_vector_type(4)));

// bf16 helpers (RNE)
__device__ __forceinline__ unsigned short f2bf(float f) {
    unsigned u = __float_as_uint(f);
    u += 0x7fffu + ((u >> 16) & 1u);
    return (unsigned short)(u >> 16);
}
__device__ __forceinline__ float bf2f(unsigned short h) {
    return __uint_as_float(((unsigned)h) << 16);
}

// cross-candidate merge insert: lexicographic (d, then index)
__device__ __forceinline__ void ins3lex(float d, int i,
        float& d0, int& i0, float& d1, int& i1, float& d2, int& i2) {
    bool b0 = (d < d0) || (d == d0 && i < i0);
    bool b1 = (d < d1) || (d == d1 && i < i1);
    bool b2 = (d < d2) || (d == d2 && i < i2);
    d2 = b1 ? d1 : (b2 ? d : d2);   i2 = b1 ? i1 : (b2 ? i : i2);
    d1 = b0 ? d0 : (b1 ? d : d1);   i1 = b0 ? i0 : (b1 ? i : i1);
    d0 = b0 ? d  : d0;              i0 = b0 ? i  : i0;
}

// ---------------- K_pack: center [B][M][3] -> cpk [B*M] float4{x,y,z,|c|^2} ----------------
__global__ __launch_bounds__(256) void k_pack(const float* __restrict__ center,
                                              float4* __restrict__ cpk) {
    int i = blockIdx.x * 256 + threadIdx.x;    // 0..B*M-1
    float cx = center[(size_t)i * 3 + 0];
    float cy = center[(size_t)i * 3 + 1];
    float cz = center[(size_t)i * 3 + 2];
    // ref: sum(center*center,-1): rounded squares, left-assoc, no fma
    float cc = __fadd_rn(__fadd_rn(__fmul_rn(cx, cx), __fmul_rn(cy, cy)),
                         __fmul_rn(cz, cz));
    cpk[i] = make_float4(cx, cy, cz, cc);
}

// ---------------- K_front: three_nn v9 (blocks 0..NNB-1) + transpose (rest) ----------------
// threenn: lane = point (64 pts/block), wave = 128-center slice via SCALAR loads
// (readfirstlane base -> s_load; no LDS, no vmcnt in hot loop), min/med3 update.
__global__ __launch_bounds__(512) void k_front(const float* __restrict__ feats,
                                               unsigned short* __restrict__ fm,
                                               const float* __restrict__ xyz,
                                               const float4* __restrict__ cpk,
                                               int* __restrict__ idx_ws,
                                               float* __restrict__ w_ws) {
    __shared__ float4 shb[1040];   // 16.64 KB: transpose tile[64][65] f32 / threenn cand[8][64][6] dwords
    int bid = blockIdx.x;
    int t   = threadIdx.x;

    if (bid >= NNB) {
        // ---- transpose role: feats [B][C][M] f32 -> fm [B][M][C] bf16 ----
        float* tile = (float*)shb;           // [64][65]
        int tb = bid - NNB;                  // 0..TRB-1
        int within = tb % ((M_ / 64) * (C_ / 64));
        int b  = tb / ((M_ / 64) * (C_ / 64));
        int mb = within & 15;
        int cb = within >> 4;                // 0..17
        int m0 = mb * 64;
        int c0 = cb * 64;
        int tx = t & 63;
        int ty = t >> 6;                     // 0..7
        const float* src = feats + ((size_t)b * C_ + c0) * M_ + m0;
#pragma unroll
        for (int j = 0; j < 8; ++j) {
            int cl = ty + 8 * j;
            tile[cl * 65 + tx] = __builtin_nontemporal_load(&src[(size_t)cl * M_ + tx]);
        }
        __syncthreads();
        unsigned short* dst = fm + ((size_t)b * M_ + m0) * C_ + c0;
#pragma unroll
        for (int j = 0; j < 8; ++j) {
            int ml = ty + 8 * j;
            dst[(size_t)ml * C_ + tx] = f2bf(tile[tx * 65 + ml]);
        }
        return;
    }

    // ---- three_nn v9 role ----
    int b  = bid >> 7;           // 128 blocks per batch
    int n0 = (bid & 127) * 64;
    int w  = t >> 6;             // 0..7: wave = center slice
    int l  = t & 63;             // lane = point
    int n  = n0 + l;

    const float* xp = xyz + ((size_t)b * N_ + n) * 3;
    float x = xp[0], y = xp[1], z = xp[2];
    float xx = __fadd_rn(__fadd_rn(__fmul_rn(x, x), __fmul_rn(y, y)),
                         __fmul_rn(z, z));

    // wave-uniform base -> scalar (SMEM) loads in the hot loop
    int cbase = __builtin_amdgcn_readfirstlane(b * M_ + w * CW);
    int mbase = __builtin_amdgcn_readfirstlane(w * CW);

    float d0 = __builtin_inff(), d1 = __builtin_inff(), d2 = __builtin_inff();
    int   i0 = 0x7fffffff,  i1 = 0x7fffffff,  i2 = 0x7fffffff;
#pragma unroll 8
    for (int it = 0; it < CW; ++it) {
        float4 v = cpk[cbase + it];          // uniform address -> s_load_dwordx4
        int m = mbase + it;                  // increasing per lane -> strict < stable
        // ref einsum: fma dot; d = (xx+cc) - 2*dot. 2*dot is exact (exp bump),
        // so fma(-2,dot,xx+cc) == fsub(fadd(xx,cc), fmul(2,dot)) bit-exactly.
        float dot = __fmaf_rn(z, v.z, __fmaf_rn(y, v.y, __fmul_rn(x, v.x)));
        float s0  = __fadd_rn(xx, v.w);
        float d   = __fmaf_rn(-2.0f, dot, s0);
        // top-3 update: d-path via min/med3 (value-identical to select cascade)
        bool b0 = d < d0;
        bool b1 = d < d1;
        bool b2 = d < d2;
        float nd0 = fminf(d, d0);
        float nd1 = __builtin_amdgcn_fmed3f(d, d0, d1);
        float nd2 = __builtin_amdgcn_fmed3f(d, d1, d2);
        i2 = b1 ? i1 : (b2 ? m : i2);
        i1 = b0 ? i0 : (b1 ? m : i1);
        i0 = b0 ? m  : i0;
        d0 = nd0; d1 = nd1; d2 = nd2;
    }

    // write candidates: cand[w][l][6] dwords (stride 6 -> 4-way aliasing, minor)
    float* cand = (float*)shb;
    int cb2 = (w * 64 + l) * 6;
    cand[cb2 + 0] = d0; ((int*)cand)[cb2 + 1] = i0;
    cand[cb2 + 2] = d1; ((int*)cand)[cb2 + 3] = i1;
    cand[cb2 + 4] = d2; ((int*)cand)[cb2 + 5] = i2;
    __syncthreads();

    if (w == 0) {
        float D0 = __builtin_inff(), D1 = __builtin_inff(), D2 = __builtin_inff();
        int   I0 = 0x7fffffff,  I1 = 0x7fffffff,  I2 = 0x7fffffff;
#pragma unroll
        for (int ww = 0; ww < 8; ++ww) {
            int rb = (ww * 64 + l) * 6;
            float e0 = cand[rb + 0]; int j0 = ((int*)cand)[rb + 1];
            float e1 = cand[rb + 2]; int j1 = ((int*)cand)[rb + 3];
            float e2 = cand[rb + 4]; int j2 = ((int*)cand)[rb + 5];
            ins3lex(e0, j0, D0, I0, D1, I1, D2, I2);
            ins3lex(e1, j1, D0, I0, D1, I1, D2, I2);
            ins3lex(e2, j2, D0, I0, D1, I1, D2, I2);
        }
        float r0 = 1.0f / __fadd_rn(D0, EPS_);
        float r1 = 1.0f / __fadd_rn(D1, EPS_);
        float r2 = 1.0f / __fadd_rn(D2, EPS_);
        float s  = __fadd_rn(__fadd_rn(r0, r1), r2);
        size_t base = ((size_t)b * N_ + n) * 3;
        idx_ws[base + 0] = I0; idx_ws[base + 1] = I1; idx_ws[base + 2] = I2;
        w_ws[base + 0] = r0 / s; w_ws[base + 1] = r1 / s; w_ws[base + 2] = r2 / s;
    }
}

// ---------------- K_interp: gather(bf16,ushort4) + weighted sum; XCD-pinned 1D grid ----------------
__global__ __launch_bounds__(256) void k_interp(const unsigned short* __restrict__ fm,
                                                const int* __restrict__ idx_ws,
                                                const float* __restrict__ w_ws,
                                                float* __restrict__ out) {
    __shared__ float T[NT][CHUNK + 1];   // stride 129
    __shared__ int   sbase[NT][3];
    __shared__ float sw[NT][3];
    int flat = blockIdx.x;
    int slot = flat & 7;
    int b    = slot >> 2;
    int idx  = (flat >> 3) * 4 + (slot & 3);   // 0..2303 per batch
    int n0   = (idx & (NBN - 1)) * NT;
    int c0   = (idx >> 8) * CHUNK;
    int t    = threadIdx.x;
    if (t < NT) {
        size_t ib = ((size_t)b * N_ + n0 + t) * 3;
#pragma unroll
        for (int k = 0; k < 3; ++k) {
            sbase[t][k] = (b * M_ + idx_ws[ib + k]) * C_;
            sw[t][k]    = w_ws[ib + k];
        }
    }
    __syncthreads();
    int wave = t >> 6;
    int lane = t & 63;
    int half = lane >> 5;
    int cl   = (lane & 31) * 4;
#pragma unroll
    for (int pp = 0; pp < 4; ++pp) {
        int p = pp * 8 + wave * 2 + half;
        float w0 = sw[p][0], w1 = sw[p][1], w2 = sw[p][2];
        const ushort4 a0 = *(const ushort4*)(fm + sbase[p][0] + c0 + cl);
        const ushort4 a1 = *(const ushort4*)(fm + sbase[p][1] + c0 + cl);
        const ushort4 a2 = *(const ushort4*)(fm + sbase[p][2] + c0 + cl);
        T[p][cl + 0] = __fmaf_rn(bf2f(a2.x), w2, __fmaf_rn(bf2f(a1.x), w1, __fmul_rn(bf2f(a0.x), w0)));
        T[p][cl + 1] = __fmaf_rn(bf2f(a2.y), w2, __fmaf_rn(bf2f(a1.y), w1, __fmul_rn(bf2f(a0.y), w0)));
        T[p][cl + 2] = __fmaf_rn(bf2f(a2.z), w2, __fmaf_rn(bf2f(a1.z), w1, __fmul_rn(bf2f(a0.z), w0)));
        T[p][cl + 3] = __fmaf_rn(bf2f(a2.w), w2, __fmaf_rn(bf2f(a1.w), w1, __fmul_rn(bf2f(a0.w), w0)));
    }
    __syncthreads();
    int p4  = (t & 7) * 4;
    int ccb = t >> 3;
#pragma unroll
    for (int r = 0; r < 4; ++r) {
        int cc = r * 32 + ccb;
        f32x4 v = { T[p4 + 0][cc], T[p4 + 1][cc], T[p4 + 2][cc], T[p4 + 3][cc] };
        __builtin_nontemporal_store(v,
            (f32x4*)&out[((size_t)b * C_ + c0 + cc) * N_ + n0 + p4]);
    }
}

// ---------------- launch ----------------
extern "C" void kernel_launch(void* const* d_in, const int* in_sizes, int n_in,
                              void* d_out, int out_size, void* d_ws, size_t ws_size,
                              hipStream_t stream) {
    const float* xyz    = (const float*)d_in[0];   // [B,N,3]
    const float* center = (const float*)d_in[1];   // [B,M,3]
    const float* feats  = (const float*)d_in[2];   // [B,C,M]
    float* out = (float*)d_out;                    // [B,C,N]

    // ws: fm bf16 | idx i32 | w f32 | cpk float4   (~5.14 MB)
    char*           ws     = (char*)d_ws;
    unsigned short* fm     = (unsigned short*)ws;
    size_t off = (size_t)B_ * M_ * C_ * 2;
    int*            idx_ws = (int*)(ws + off);      off += (size_t)B_ * N_ * 3 * 4;
    float*          w_ws   = (float*)(ws + off);    off += (size_t)B_ * N_ * 3 * 4;
    float4*         cpk    = (float4*)(ws + off);

    k_pack  <<<(B_ * M_) / 256, 256, 0, stream>>>(center, cpk);
    k_front <<<NNB + TRB, 512, 0, stream>>>(feats, fm, xyz, cpk, idx_ws, w_ws);
    k_interp<<<NBN * NBC * B_, 256, 0, stream>>>(fm, idx_ws, w_ws, out);
}